// Round 7
// baseline (611.268 us; speedup 1.0000x reference)
//
#include <hip/hip_runtime.h>

#define T_DIM 512
#define B_DIM 512
#define OBS_DIM 128
#define H_DIM 128
#define A_DIM 18
#define G3 384
#define LDSS 136        // LDS row stride in halfs (128 + 8 pad, 16B-aligned rows)
#define K1_ITERS 8      // 512 blocks x 8 tiles of 64 rows

// exp-argument scales folded into weights/biases/stored gi:
//  r,z gates: arg' = -log2e * arg   (sigmoid(x) = 1/(1+2^(arg')))
//  n gate:    arg' = 2*log2e * arg  (tanh(x) = (2^(arg')-1)/(2^(arg')+1))
#define SC_R (-1.44269504088896f)
#define SC_N (2.88539008177793f)

typedef _Float16 v8h __attribute__((ext_vector_type(8)));
typedef _Float16 v4h __attribute__((ext_vector_type(4)));
typedef _Float16 v2h __attribute__((ext_vector_type(2)));
typedef float v4f __attribute__((ext_vector_type(4)));
typedef float v2f __attribute__((ext_vector_type(2)));

#define EXP2F(x) __builtin_amdgcn_exp2f(x)
#define RCPF(x)  __builtin_amdgcn_rcpf(x)
#define PKRTZ(a,b) __builtin_bit_cast(v2h, __builtin_amdgcn_cvt_pkrtz((a),(b)))

// LDS-only barrier: drains lgkmcnt but leaves vmcnt in flight.
#define BAR() asm volatile("s_waitcnt lgkmcnt(0)\n\ts_barrier" ::: "memory")

// ---------------------------------------------------------------------------
// K1: gi = relu(obs @ W_emb + b_emb) @ Wi + bi, stored f16 PRE-SCALED.
// This round: 512 blocks (2/CU for latency overlap), __launch_bounds__(512,4)
// caps VGPR at 128 so both blocks are resident; biases folded into MFMA
// C-init (no epilogue adds).
// ---------------------------------------------------------------------------
__global__ __launch_bounds__(512, 4) void k1_embed_gi(
    const float* __restrict__ obs,
    const float* __restrict__ W_emb,
    const float* __restrict__ b_emb,
    const float* __restrict__ Wi,
    const float* __restrict__ bi,
    _Float16* __restrict__ gRZ,
    _Float16* __restrict__ gN)
{
    __shared__ __align__(16) _Float16 obs_lds[64 * LDSS];   // 17408 B
    __shared__ __align__(16) _Float16 emb_lds[64 * LDSS];   // 17408 B
    const int tid  = threadIdx.x;
    const int cg   = tid >> 6;     // wave = col-group
    const int lane = tid & 63;
    const int n16  = lane & 15;
    const int quad = lane >> 4;

    // A-frags: lane holds A[m=n16][k=kt*32+quad*8+j]; gate scales folded in.
    v8h fe[4];
    v8h fi[3][4];
#pragma unroll
    for (int kt = 0; kt < 4; ++kt)
#pragma unroll
        for (int j = 0; j < 8; ++j) {
            const int k = kt * 32 + quad * 8 + j;
            fe[kt][j] = (_Float16)W_emb[k * H_DIM + cg * 16 + n16];
        }
#pragma unroll
    for (int g = 0; g < 3; ++g) {
        const float sc = (g == 2) ? SC_N : SC_R;
#pragma unroll
        for (int kt = 0; kt < 4; ++kt)
#pragma unroll
            for (int j = 0; j < 8; ++j) {
                const int k = kt * 32 + quad * 8 + j;
                fi[g][kt][j] = (_Float16)(Wi[k * G3 + g * H_DIM + cg * 16 + n16] * sc);
            }
    }
    // biases as MFMA C-init vectors (acc reg r <-> col quad*4+r; uniform over rows)
    v4f bemb_c, bir_c, biz_c, bin_c;
#pragma unroll
    for (int r = 0; r < 4; ++r) {
        const int col = cg * 16 + quad * 4 + r;
        bemb_c[r] = b_emb[col];
        bir_c[r]  = bi[col] * SC_R;
        biz_c[r]  = bi[H_DIM + col] * SC_R;
        bin_c[r]  = bi[2 * H_DIM + col] * SC_N;
    }

    const int srow = tid >> 3;          // 0..63
    const int sk   = (tid & 7) * 16;    // 0..112 (16 floats per thread)
    const int base = blockIdx.x * K1_ITERS;

    // stage iter 0's obs
    {
        const float* op = obs + (size_t)(base * 64 + srow) * OBS_DIM + sk;
#pragma unroll
        for (int q = 0; q < 4; ++q) {
            const float4 a = *(const float4*)(op + q * 4);
            v4h pa = { (_Float16)a.x, (_Float16)a.y, (_Float16)a.z, (_Float16)a.w };
            *(v4h*)&obs_lds[srow * LDSS + sk + q * 4] = pa;
        }
    }
    __syncthreads();

    for (int i = 0; i < K1_ITERS; ++i) {
        const int row0 = (base + i) * 64;
        const int ni = (i + 1 < K1_ITERS) ? i + 1 : i;
        const float* opn = obs + (size_t)((base + ni) * 64 + srow) * OBS_DIM + sk;
        float4 nv[4];
#pragma unroll
        for (int q = 0; q < 4; ++q) nv[q] = *(const float4*)(opn + q * 4);

        // phase A: emb, 4 row-tiles x 16 cols per wave
#pragma unroll
        for (int rt = 0; rt < 4; ++rt) {
            v8h bo[4];
#pragma unroll
            for (int kt = 0; kt < 4; ++kt)
                bo[kt] = *(const v8h*)&obs_lds[(rt * 16 + n16) * LDSS + kt * 32 + quad * 8];
            v4f ea = bemb_c;
#pragma unroll
            for (int kt = 0; kt < 4; ++kt)
                ea = __builtin_amdgcn_mfma_f32_16x16x32_f16(fe[kt], bo[kt], ea, 0, 0, 0);
            v4h e;
#pragma unroll
            for (int r = 0; r < 4; ++r) e[r] = (_Float16)fmaxf(ea[r], 0.f);
            *(v4h*)&emb_lds[(rt * 16 + n16) * LDSS + cg * 16 + quad * 4] = e;
        }
        BAR();
        // phase B: gi, 4 row-tiles x 3 gates x 16 cols per wave
#pragma unroll
        for (int rt = 0; rt < 4; ++rt) {
            v8h be[4];
#pragma unroll
            for (int kt = 0; kt < 4; ++kt)
                be[kt] = *(const v8h*)&emb_lds[(rt * 16 + n16) * LDSS + kt * 32 + quad * 8];
            v4f ar = bir_c, az = biz_c, an = bin_c;
#pragma unroll
            for (int kt = 0; kt < 4; ++kt) {
                ar = __builtin_amdgcn_mfma_f32_16x16x32_f16(fi[0][kt], be[kt], ar, 0, 0, 0);
                az = __builtin_amdgcn_mfma_f32_16x16x32_f16(fi[1][kt], be[kt], az, 0, 0, 0);
                an = __builtin_amdgcn_mfma_f32_16x16x32_f16(fi[2][kt], be[kt], an, 0, 0, 0);
            }
            const int R = row0 + rt * 16 + n16;
            v8h rz;
#pragma unroll
            for (int r = 0; r < 4; ++r) {
                rz[r]     = (_Float16)ar[r];
                rz[4 + r] = (_Float16)az[r];
            }
            *(v8h*)&gRZ[(size_t)R * 256 + cg * 32 + quad * 8] = rz;
            v4h nn;
#pragma unroll
            for (int r = 0; r < 4; ++r) nn[r] = (_Float16)an[r];
            *(v4h*)&gN[(size_t)R * 128 + cg * 16 + quad * 4] = nn;
        }
        // stage next iter's obs (obs_lds reads all ended before the mid BAR)
#pragma unroll
        for (int q = 0; q < 4; ++q) {
            v4h pa = { (_Float16)nv[q].x, (_Float16)nv[q].y, (_Float16)nv[q].z, (_Float16)nv[q].w };
            *(v4h*)&obs_lds[srow * LDSS + sk + q * 4] = pa;
        }
        BAR();
    }
}

// ---------------------------------------------------------------------------
// K2: GRU recurrence + INLINE q-output (absorbs K3). Unchanged from round 6.
// ---------------------------------------------------------------------------
__global__ __launch_bounds__(512) void k2_recurrence(
    const float* __restrict__ hidden,
    const unsigned char* __restrict__ dones_raw,
    const _Float16* __restrict__ gRZ,
    const _Float16* __restrict__ gN,
    const float* __restrict__ Wh,
    const float* __restrict__ bhn,
    const float* __restrict__ W_out,
    const float* __restrict__ b_out,
    float* __restrict__ out)
{
    __shared__ __align__(16) _Float16 h_lds[2][16 * LDSS];
    __shared__ __align__(16) unsigned char d_lds[(T_DIM + 1) * 16];
    __shared__ int byte_mode;
    const int tid  = threadIdx.x;
    const int w    = tid >> 6;
    const int lane = tid & 63;
    const int n16  = lane & 15;   // batch within group
    const int quad = lane >> 4;
    const int c16  = w * 16 + quad * 4;
    const int B0   = blockIdx.x * 16;

    if (tid == 0) byte_mode = 0;
    __syncthreads();
    {   // detect dones element width: byte==1 at non-4-aligned offset => 1-byte bools
        int hit = 0;
        for (int i = tid; i < 4096; i += 512)
            if ((i & 3) != 0 && dones_raw[i] == 1) hit = 1;
        if (hit) byte_mode = 1;
    }
    __syncthreads();
    const bool bm = (byte_mode != 0);

    // stage this block's dones slice: d_lds[t*16 + b]; row T zeroed
    {
        if (bm) {
            const int4 v = *(const int4*)(dones_raw + (size_t)tid * B_DIM + B0);
            *(int4*)&d_lds[tid * 16] = v;
        } else {
            const int* di = (const int*)dones_raw;
            const int* pp = di + (size_t)tid * B_DIM + B0;
            int4 wv; unsigned char* wb = (unsigned char*)&wv;
#pragma unroll
            for (int j = 0; j < 16; ++j) wb[j] = (unsigned char)(pp[j] != 0);
            *(int4*)&d_lds[tid * 16] = wv;
        }
        if (tid == 0) { int4 z = {0,0,0,0}; *(int4*)&d_lds[T_DIM * 16] = z; }
    }

    // Wh^T A-frags, gate scales folded in
    v8h fh[3][4];
#pragma unroll
    for (int g = 0; g < 3; ++g) {
        const float sc = (g == 2) ? SC_N : SC_R;
#pragma unroll
        for (int kt = 0; kt < 4; ++kt)
#pragma unroll
            for (int j = 0; j < 8; ++j) {
                const int k = kt * 32 + quad * 8 + j;
                fh[g][kt][j] = (_Float16)(Wh[k * G3 + g * H_DIM + w * 16 + n16] * sc);
            }
    }
    // bhn folded into n-gate accumulator C-init
    const v4f bhn_c = { bhn[c16] * SC_N, bhn[c16 + 1] * SC_N,
                        bhn[c16 + 2] * SC_N, bhn[c16 + 3] * SC_N };

    // q-output frags for waves 0,1: A[m=qcol][k], qcol = w*16+n16 (0 if >=18)
    v8h fo[4];
    float bq[4];
    if (w < 2) {
        const int col = w * 16 + n16;
#pragma unroll
        for (int kt = 0; kt < 4; ++kt)
#pragma unroll
            for (int j = 0; j < 8; ++j) {
                const int k = kt * 32 + quad * 8 + j;
                fo[kt][j] = (col < A_DIM) ? (_Float16)W_out[k * A_DIM + col] : (_Float16)0.f;
            }
#pragma unroll
        for (int r = 0; r < 4; ++r) {
            const int c = w * 16 + quad * 4 + r;
            bq[r] = (c < A_DIM) ? b_out[c] : 0.f;
        }
    }
    float* qout = out + (size_t)B_DIM * H_DIM;

    __syncthreads();   // d_lds visible

    // init carry, pre-masked with done[0]; h_lds[0] holds the SAME (masked)
    // value, so step 0 uses dprev=0 (no gate-mask needed).
    const bool d0 = d_lds[n16] != 0;
    v4f huv;
#pragma unroll
    for (int r = 0; r < 4; ++r) {
        const float hv = hidden[(size_t)(B0 + n16) * H_DIM + c16 + r];
        huv[r] = d0 ? 0.f : hv;
    }
    {
        v2h h01 = PKRTZ(huv[0], huv[1]);
        v2h h23 = PKRTZ(huv[2], huv[3]);
        v4h hw = { h01[0], h01[1], h23[0], h23[1] };
        *(v4h*)&h_lds[0][n16 * LDSS + c16] = hw;
    }

    // uniform (SGPR) stream bases + constant per-lane 32-bit byte offsets
    const int RZB = B_DIM * 256 * 2;   // bytes per t-row of gRZ
    const int NB  = B_DIM * 128 * 2;   // bytes per t-row of gN
    const int rzo = ((B0 + n16) * 256 + w * 32 + quad * 8) * 2;
    const int no_ = ((B0 + n16) * 128 + c16) * 2;
    const char* gRZc = (const char*)gRZ;
    const char* gNc  = (const char*)gN;

    // 4-deep rotating prefetch buffers, preloaded with rows 0..3
    v8h s8a = *(const v8h*)(gRZc + 0 * (size_t)RZB + rzo);
    v8h s8b = *(const v8h*)(gRZc + 1 * (size_t)RZB + rzo);
    v8h s8c = *(const v8h*)(gRZc + 2 * (size_t)RZB + rzo);
    v8h s8d = *(const v8h*)(gRZc + 3 * (size_t)RZB + rzo);
    v4h s4a = *(const v4h*)(gNc + 0 * (size_t)NB + no_);
    v4h s4b = *(const v4h*)(gNc + 1 * (size_t)NB + no_);
    v4h s4c = *(const v4h*)(gNc + 2 * (size_t)NB + no_);
    v4h s4d = *(const v4h*)(gNc + 3 * (size_t)NB + no_);

    const char* rzb = gRZc + (size_t)4 * RZB;   // prefetch base (row t+4)
    const char* nb  = gNc  + (size_t)4 * NB;
    int dpo = 16 + n16;                         // d_lds offset for done[t+1]
    bool dprev = false;                         // done[t] (h_lds[0] pre-masked)
    __syncthreads();   // h_lds[0] visible

    auto STEP = [&](int t, v8h& s8, v4h& s4,
                    const _Float16* __restrict__ hin, _Float16* __restrict__ hout)
        __attribute__((always_inline)) -> void {
        const unsigned char dnx = d_lds[dpo];

        v8h bh[4];
#pragma unroll
        for (int kt = 0; kt < 4; ++kt)
            bh[kt] = *(const v8h*)&hin[n16 * LDSS + kt * 32 + quad * 8];

        // --- inline q[t-1] on waves 0,1 (bh IS unmasked ys[t-1]) ---
        if (w < 2) {
            v4f qa = {0.f,0.f,0.f,0.f};
#pragma unroll
            for (int kt = 0; kt < 4; ++kt)
                qa = __builtin_amdgcn_mfma_f32_16x16x32_f16(fo[kt], bh[kt], qa, 0, 0, 0);
            if (t > 0) {
                float* qp = qout + ((size_t)(t - 1) * B_DIM + B0 + n16) * A_DIM;
                const int cbase = w * 16 + quad * 4;
#pragma unroll
                for (int r = 0; r < 4; ++r)
                    if (cbase + r < A_DIM) qp[cbase + r] = qa[r] + bq[r];
            }
        }

        // --- gate 0 (r) MFMA chain ---
        v4f ga0 = {0.f,0.f,0.f,0.f};
#pragma unroll
        for (int kt = 0; kt < 4; ++kt)
            ga0 = __builtin_amdgcn_mfma_f32_16x16x32_f16(fh[0][kt], bh[kt], ga0, 0, 0, 0);
        // --- gate 1 (z) MFMA chain ---
        v4f ga1 = {0.f,0.f,0.f,0.f};
#pragma unroll
        for (int kt = 0; kt < 4; ++kt)
            ga1 = __builtin_amdgcn_mfma_f32_16x16x32_f16(fh[1][kt], bh[kt], ga1, 0, 0, 0);

        // gate-mask for done rows (replaces carry masking in h_lds):
        // lane's 4 outputs all belong to batch n16 -> per-lane cndmask.
        if (dprev) { ga0 = (v4f){0.f,0.f,0.f,0.f}; ga1 = (v4f){0.f,0.f,0.f,0.f}; }

        // r-gate trans NOW: depends only on ga0; overlaps ga2 matrix-pipe time
        v2f arl = (v2f){ (float)s8[0], (float)s8[1] } + (v2f){ ga0[0], ga0[1] };
        v2f arh = (v2f){ (float)s8[2], (float)s8[3] } + (v2f){ ga0[2], ga0[3] };
        v2f rgl = { RCPF(EXP2F(arl[0]) + 1.f), RCPF(EXP2F(arl[1]) + 1.f) };
        v2f rgh = { RCPF(EXP2F(arh[0]) + 1.f), RCPF(EXP2F(arh[1]) + 1.f) };

        // --- gate 2 (n) MFMA chain, bhn in C-init ---
        v4f ga2 = bhn_c;
#pragma unroll
        for (int kt = 0; kt < 4; ++kt)
            ga2 = __builtin_amdgcn_mfma_f32_16x16x32_f16(fh[2][kt], bh[kt], ga2, 0, 0, 0);
        if (dprev) ga2 = bhn_c;

        // z-gate trans: depends only on ga1; overlaps ga2's tail
        v2f azl = (v2f){ (float)s8[4], (float)s8[5] } + (v2f){ ga1[0], ga1[1] };
        v2f azh = (v2f){ (float)s8[6], (float)s8[7] } + (v2f){ ga1[2], ga1[3] };
        v2f ezl = { EXP2F(azl[0]), EXP2F(azl[1]) };
        v2f ezh = { EXP2F(azh[0]), EXP2F(azh[1]) };

        // n-gate + fused rational: h = [ez*(en-1) + hu*(en+1)] / [(en+1)*(1+ez)]
        v2f snl = rgl * (v2f){ ga2[0], ga2[1] } + (v2f){ (float)s4[0], (float)s4[1] };
        v2f snh = rgh * (v2f){ ga2[2], ga2[3] } + (v2f){ (float)s4[2], (float)s4[3] };
        v2f enl = { EXP2F(snl[0]), EXP2F(snl[1]) };
        v2f enh = { EXP2F(snh[0]), EXP2F(snh[1]) };
        v2f enpl = enl + 1.f, enph = enh + 1.f;
        v2f enml = enl - 1.f, enmh = enh - 1.f;
        v2f hul = { huv[0], huv[1] }, huh = { huv[2], huv[3] };
        v2f numl = hul * enpl + enml * ezl;
        v2f numh = huh * enph + enmh * ezh;
        v2f denl = enpl * (ezl + 1.f);
        v2f denh = enph * (ezh + 1.f);
        v2f hnl = numl * (v2f){ RCPF(denl[0]), RCPF(denl[1]) };
        v2f hnh = numh * (v2f){ RCPF(denh[0]), RCPF(denh[1]) };

        // h_lds gets the UNMASKED ys[t]; register carry gets done[t+1] mask
        v2h y01 = PKRTZ(hnl[0], hnl[1]);
        v2h y23 = PKRTZ(hnh[0], hnh[1]);
        v4h yv = { y01[0], y01[1], y23[0], y23[1] };
        *(v4h*)&hout[n16 * LDSS + c16] = yv;
        const bool dn = dnx != 0;
#pragma unroll
        for (int r = 0; r < 4; ++r) huv[r] = dn ? 0.f : (r < 2 ? hnl[r] : hnh[r - 2]);
        dprev = dn;

        // reload THIS buffer with row t+4 (consumed 4 steps later)
        s8 = *(const v8h*)(rzb + rzo);
        s4 = *(const v4h*)(nb + no_);

        if (t < 507) { rzb += RZB; nb += NB; }
        dpo += 16;
        BAR();
    };

    for (int t = 0; t < T_DIM; t += 4) {
        STEP(t,     s8a, s4a, h_lds[0], h_lds[1]);
        STEP(t + 1, s8b, s4b, h_lds[1], h_lds[0]);
        STEP(t + 2, s8c, s4c, h_lds[0], h_lds[1]);
        STEP(t + 3, s8d, s4d, h_lds[1], h_lds[0]);
    }

    // epilogue: q[511] from h_lds[0] (written by STEP(511); BAR() done)
    if (w < 2) {
        v8h bh[4];
#pragma unroll
        for (int kt = 0; kt < 4; ++kt)
            bh[kt] = *(const v8h*)&h_lds[0][n16 * LDSS + kt * 32 + quad * 8];
        v4f qa = {0.f,0.f,0.f,0.f};
#pragma unroll
        for (int kt = 0; kt < 4; ++kt)
            qa = __builtin_amdgcn_mfma_f32_16x16x32_f16(fo[kt], bh[kt], qa, 0, 0, 0);
        float* qp = qout + ((size_t)(T_DIM - 1) * B_DIM + B0 + n16) * A_DIM;
        const int cbase = w * 16 + quad * 4;
#pragma unroll
        for (int r = 0; r < 4; ++r)
            if (cbase + r < A_DIM) qp[cbase + r] = qa[r] + bq[r];
    }

    // h_final (hu after t=511 is unmasked: d_lds row 512 zeroed)
#pragma unroll
    for (int r = 0; r < 4; ++r)
        out[(size_t)(B0 + n16) * H_DIM + c16 + r] = huv[r];
}

extern "C" void kernel_launch(void* const* d_in, const int* in_sizes, int n_in,
                              void* d_out, int out_size, void* d_ws, size_t ws_size,
                              hipStream_t stream) {
    const float* hidden = (const float*)d_in[0];
    const float* obs    = (const float*)d_in[1];
    const unsigned char* dones = (const unsigned char*)d_in[2];
    const float* W_emb  = (const float*)d_in[3];
    const float* b_emb  = (const float*)d_in[4];
    const float* Wi     = (const float*)d_in[5];
    const float* bi     = (const float*)d_in[6];
    const float* Wh     = (const float*)d_in[7];
    const float* bhn    = (const float*)d_in[8];
    const float* W_out  = (const float*)d_in[9];
    const float* b_out  = (const float*)d_in[10];
    float* out = (float*)d_out;

    _Float16* gRZ = (_Float16*)d_ws;                              // [T*B][256] f16 = 128 MiB
    _Float16* gN  = gRZ + (size_t)T_DIM * B_DIM * 256;            // [T*B][128] f16 =  64 MiB

    hipLaunchKernelGGL(k1_embed_gi, dim3(512), dim3(512), 0, stream,
                       obs, W_emb, b_emb, Wi, bi, gRZ, gN);
    hipLaunchKernelGGL(k2_recurrence, dim3(32), dim3(512), 0, stream,
                       hidden, dones, gRZ, gN, Wh, bhn, W_out, b_out, out);
}

// Round 8
// 591.076 us; speedup vs baseline: 1.0342x; 1.0342x over previous
//
#include <hip/hip_runtime.h>

#define T_DIM 512
#define B_DIM 512
#define OBS_DIM 128
#define H_DIM 128
#define A_DIM 18
#define G3 384
#define LDSS 136        // LDS row stride in halfs (128 + 8 pad, 16B-aligned rows)
#define K1_ITERS 16     // 256 blocks x 16 tiles of 64 rows

// exp-argument scales folded into weights/biases/stored gi:
//  r,z gates: arg' = -log2e * arg   (sigmoid(x) = 1/(1+2^(arg')))
//  n gate:    arg' = 2*log2e * arg  (tanh(x) = (2^(arg')-1)/(2^(arg')+1))
#define SC_R (-1.44269504088896f)
#define SC_N (2.88539008177793f)

typedef _Float16 v8h __attribute__((ext_vector_type(8)));
typedef _Float16 v4h __attribute__((ext_vector_type(4)));
typedef _Float16 v2h __attribute__((ext_vector_type(2)));
typedef float v4f __attribute__((ext_vector_type(4)));
typedef float v2f __attribute__((ext_vector_type(2)));

#define EXP2F(x) __builtin_amdgcn_exp2f(x)
#define RCPF(x)  __builtin_amdgcn_rcpf(x)
#define PKRTZ(a,b) __builtin_bit_cast(v2h, __builtin_amdgcn_cvt_pkrtz((a),(b)))

// LDS-only barrier: drains lgkmcnt but leaves vmcnt in flight.
#define BAR() asm volatile("s_waitcnt lgkmcnt(0)\n\ts_barrier" ::: "memory")

// ---------------------------------------------------------------------------
// K1: gi = relu(obs @ W_emb + b_emb) @ Wi + bi, stored f16 PRE-SCALED.
// This round: SINGLE-BARRIER software pipeline. Per barrier region:
//   phase B(i)  : gi(i)   from emb_lds[cur]   (48 MFMA/wave)
//   phase A(i+1): emb(i+1) from obs_lds[nxt]  (16 MFMA/wave, independent tree)
//   stage obs(i+2) -> obs_lds[cur]
// Double-buffered obs/emb LDS (69632 B). Barriers per block: 32 -> 17.
// Grid back to 256 blocks (1/CU), no min-occupancy clause (round-7 lesson).
// ---------------------------------------------------------------------------
__global__ __launch_bounds__(512) void k1_embed_gi(
    const float* __restrict__ obs,
    const float* __restrict__ W_emb,
    const float* __restrict__ b_emb,
    const float* __restrict__ Wi,
    const float* __restrict__ bi,
    _Float16* __restrict__ gRZ,
    _Float16* __restrict__ gN)
{
    __shared__ __align__(16) _Float16 obs_lds[2][64 * LDSS];   // 2 x 17408 B
    __shared__ __align__(16) _Float16 emb_lds[2][64 * LDSS];   // 2 x 17408 B
    const int tid  = threadIdx.x;
    const int cg   = tid >> 6;     // wave = col-group
    const int lane = tid & 63;
    const int n16  = lane & 15;
    const int quad = lane >> 4;

    // A-frags: lane holds A[m=n16][k=kt*32+quad*8+j]; gate scales folded in.
    v8h fe[4];
    v8h fi[3][4];
#pragma unroll
    for (int kt = 0; kt < 4; ++kt)
#pragma unroll
        for (int j = 0; j < 8; ++j) {
            const int k = kt * 32 + quad * 8 + j;
            fe[kt][j] = (_Float16)W_emb[k * H_DIM + cg * 16 + n16];
        }
#pragma unroll
    for (int g = 0; g < 3; ++g) {
        const float sc = (g == 2) ? SC_N : SC_R;
#pragma unroll
        for (int kt = 0; kt < 4; ++kt)
#pragma unroll
            for (int j = 0; j < 8; ++j) {
                const int k = kt * 32 + quad * 8 + j;
                fi[g][kt][j] = (_Float16)(Wi[k * G3 + g * H_DIM + cg * 16 + n16] * sc);
            }
    }
    // biases as MFMA C-init vectors
    v4f bemb_c, bir_c, biz_c, bin_c;
#pragma unroll
    for (int r = 0; r < 4; ++r) {
        const int col = cg * 16 + quad * 4 + r;
        bemb_c[r] = b_emb[col];
        bir_c[r]  = bi[col] * SC_R;
        biz_c[r]  = bi[H_DIM + col] * SC_R;
        bin_c[r]  = bi[2 * H_DIM + col] * SC_N;
    }

    const int srow = tid >> 3;          // 0..63
    const int sk   = (tid & 7) * 16;    // 0..112 (16 floats per thread)
    const int base = blockIdx.x * K1_ITERS;

    // ---- prologue: stage obs(0) -> buf0 ----
    {
        const float* op = obs + (size_t)(base * 64 + srow) * OBS_DIM + sk;
#pragma unroll
        for (int q = 0; q < 4; ++q) {
            const float4 a = *(const float4*)(op + q * 4);
            v4h pa = { (_Float16)a.x, (_Float16)a.y, (_Float16)a.z, (_Float16)a.w };
            *(v4h*)&obs_lds[0][srow * LDSS + sk + q * 4] = pa;
        }
    }
    __syncthreads();

    // ---- prologue: emb(0) from buf0 -> emb0; stage obs(1) -> buf1 ----
    {
        const float* op1 = obs + (size_t)((base + 1) * 64 + srow) * OBS_DIM + sk;
        float4 nv[4];
#pragma unroll
        for (int q = 0; q < 4; ++q) nv[q] = *(const float4*)(op1 + q * 4);

#pragma unroll
        for (int rt = 0; rt < 4; ++rt) {
            v8h bo[4];
#pragma unroll
            for (int kt = 0; kt < 4; ++kt)
                bo[kt] = *(const v8h*)&obs_lds[0][(rt * 16 + n16) * LDSS + kt * 32 + quad * 8];
            v4f ea = bemb_c;
#pragma unroll
            for (int kt = 0; kt < 4; ++kt)
                ea = __builtin_amdgcn_mfma_f32_16x16x32_f16(fe[kt], bo[kt], ea, 0, 0, 0);
            v4h e;
#pragma unroll
            for (int r = 0; r < 4; ++r) e[r] = (_Float16)fmaxf(ea[r], 0.f);
            *(v4h*)&emb_lds[0][(rt * 16 + n16) * LDSS + cg * 16 + quad * 4] = e;
        }
#pragma unroll
        for (int q = 0; q < 4; ++q) {
            v4h pa = { (_Float16)nv[q].x, (_Float16)nv[q].y, (_Float16)nv[q].z, (_Float16)nv[q].w };
            *(v4h*)&obs_lds[1][srow * LDSS + sk + q * 4] = pa;
        }
    }
    BAR();

    // ---- main loop: ONE barrier per 64-row tile ----
    for (int i = 0; i < K1_ITERS; ++i) {
        const int cur = i & 1, nxt = cur ^ 1;
        const int row0 = (base + i) * 64;

        // prefetch obs(i+2) -> regs (clamped; last iters restage tile 15)
        const int pi = (i + 2 < K1_ITERS) ? i + 2 : K1_ITERS - 1;
        const float* opn = obs + (size_t)((base + pi) * 64 + srow) * OBS_DIM + sk;
        float4 nv[4];
#pragma unroll
        for (int q = 0; q < 4; ++q) nv[q] = *(const float4*)(opn + q * 4);

        // phase B: gi(i) from emb_lds[cur] (48 MFMA/wave)
#pragma unroll
        for (int rt = 0; rt < 4; ++rt) {
            v8h be[4];
#pragma unroll
            for (int kt = 0; kt < 4; ++kt)
                be[kt] = *(const v8h*)&emb_lds[cur][(rt * 16 + n16) * LDSS + kt * 32 + quad * 8];
            v4f ar = bir_c, az = biz_c, an = bin_c;
#pragma unroll
            for (int kt = 0; kt < 4; ++kt) {
                ar = __builtin_amdgcn_mfma_f32_16x16x32_f16(fi[0][kt], be[kt], ar, 0, 0, 0);
                az = __builtin_amdgcn_mfma_f32_16x16x32_f16(fi[1][kt], be[kt], az, 0, 0, 0);
                an = __builtin_amdgcn_mfma_f32_16x16x32_f16(fi[2][kt], be[kt], an, 0, 0, 0);
            }
            const int R = row0 + rt * 16 + n16;
            v8h rz;
#pragma unroll
            for (int r = 0; r < 4; ++r) {
                rz[r]     = (_Float16)ar[r];
                rz[4 + r] = (_Float16)az[r];
            }
            *(v8h*)&gRZ[(size_t)R * 256 + cg * 32 + quad * 8] = rz;
            v4h nn;
#pragma unroll
            for (int r = 0; r < 4; ++r) nn[r] = (_Float16)an[r];
            *(v4h*)&gN[(size_t)R * 128 + cg * 16 + quad * 4] = nn;
        }

        // phase A: emb(i+1) from obs_lds[nxt] -> emb_lds[nxt] (independent tree;
        // at i = K1_ITERS-1 this recomputes emb(15) into the dead buffer — harmless)
#pragma unroll
        for (int rt = 0; rt < 4; ++rt) {
            v8h bo[4];
#pragma unroll
            for (int kt = 0; kt < 4; ++kt)
                bo[kt] = *(const v8h*)&obs_lds[nxt][(rt * 16 + n16) * LDSS + kt * 32 + quad * 8];
            v4f ea = bemb_c;
#pragma unroll
            for (int kt = 0; kt < 4; ++kt)
                ea = __builtin_amdgcn_mfma_f32_16x16x32_f16(fe[kt], bo[kt], ea, 0, 0, 0);
            v4h e;
#pragma unroll
            for (int r = 0; r < 4; ++r) e[r] = (_Float16)fmaxf(ea[r], 0.f);
            *(v4h*)&emb_lds[nxt][(rt * 16 + n16) * LDSS + cg * 16 + quad * 4] = e;
        }

        // stage obs(i+2) -> obs_lds[cur] (obs(i) reads ended last iter, pre-BAR)
#pragma unroll
        for (int q = 0; q < 4; ++q) {
            v4h pa = { (_Float16)nv[q].x, (_Float16)nv[q].y, (_Float16)nv[q].z, (_Float16)nv[q].w };
            *(v4h*)&obs_lds[cur][srow * LDSS + sk + q * 4] = pa;
        }
        BAR();
    }
}

// ---------------------------------------------------------------------------
// K2: GRU recurrence + INLINE q-output (absorbs K3). Unchanged from round 6.
// ---------------------------------------------------------------------------
__global__ __launch_bounds__(512) void k2_recurrence(
    const float* __restrict__ hidden,
    const unsigned char* __restrict__ dones_raw,
    const _Float16* __restrict__ gRZ,
    const _Float16* __restrict__ gN,
    const float* __restrict__ Wh,
    const float* __restrict__ bhn,
    const float* __restrict__ W_out,
    const float* __restrict__ b_out,
    float* __restrict__ out)
{
    __shared__ __align__(16) _Float16 h_lds[2][16 * LDSS];
    __shared__ __align__(16) unsigned char d_lds[(T_DIM + 1) * 16];
    __shared__ int byte_mode;
    const int tid  = threadIdx.x;
    const int w    = tid >> 6;
    const int lane = tid & 63;
    const int n16  = lane & 15;   // batch within group
    const int quad = lane >> 4;
    const int c16  = w * 16 + quad * 4;
    const int B0   = blockIdx.x * 16;

    if (tid == 0) byte_mode = 0;
    __syncthreads();
    {   // detect dones element width: byte==1 at non-4-aligned offset => 1-byte bools
        int hit = 0;
        for (int i = tid; i < 4096; i += 512)
            if ((i & 3) != 0 && dones_raw[i] == 1) hit = 1;
        if (hit) byte_mode = 1;
    }
    __syncthreads();
    const bool bm = (byte_mode != 0);

    // stage this block's dones slice: d_lds[t*16 + b]; row T zeroed
    {
        if (bm) {
            const int4 v = *(const int4*)(dones_raw + (size_t)tid * B_DIM + B0);
            *(int4*)&d_lds[tid * 16] = v;
        } else {
            const int* di = (const int*)dones_raw;
            const int* pp = di + (size_t)tid * B_DIM + B0;
            int4 wv; unsigned char* wb = (unsigned char*)&wv;
#pragma unroll
            for (int j = 0; j < 16; ++j) wb[j] = (unsigned char)(pp[j] != 0);
            *(int4*)&d_lds[tid * 16] = wv;
        }
        if (tid == 0) { int4 z = {0,0,0,0}; *(int4*)&d_lds[T_DIM * 16] = z; }
    }

    // Wh^T A-frags, gate scales folded in
    v8h fh[3][4];
#pragma unroll
    for (int g = 0; g < 3; ++g) {
        const float sc = (g == 2) ? SC_N : SC_R;
#pragma unroll
        for (int kt = 0; kt < 4; ++kt)
#pragma unroll
            for (int j = 0; j < 8; ++j) {
                const int k = kt * 32 + quad * 8 + j;
                fh[g][kt][j] = (_Float16)(Wh[k * G3 + g * H_DIM + w * 16 + n16] * sc);
            }
    }
    // bhn folded into n-gate accumulator C-init
    const v4f bhn_c = { bhn[c16] * SC_N, bhn[c16 + 1] * SC_N,
                        bhn[c16 + 2] * SC_N, bhn[c16 + 3] * SC_N };

    // q-output frags for waves 0,1: A[m=qcol][k], qcol = w*16+n16 (0 if >=18)
    v8h fo[4];
    float bq[4];
    if (w < 2) {
        const int col = w * 16 + n16;
#pragma unroll
        for (int kt = 0; kt < 4; ++kt)
#pragma unroll
            for (int j = 0; j < 8; ++j) {
                const int k = kt * 32 + quad * 8 + j;
                fo[kt][j] = (col < A_DIM) ? (_Float16)W_out[k * A_DIM + col] : (_Float16)0.f;
            }
#pragma unroll
        for (int r = 0; r < 4; ++r) {
            const int c = w * 16 + quad * 4 + r;
            bq[r] = (c < A_DIM) ? b_out[c] : 0.f;
        }
    }
    float* qout = out + (size_t)B_DIM * H_DIM;

    __syncthreads();   // d_lds visible

    // init carry, pre-masked with done[0]; h_lds[0] holds the SAME (masked)
    // value, so step 0 uses dprev=0 (no gate-mask needed).
    const bool d0 = d_lds[n16] != 0;
    v4f huv;
#pragma unroll
    for (int r = 0; r < 4; ++r) {
        const float hv = hidden[(size_t)(B0 + n16) * H_DIM + c16 + r];
        huv[r] = d0 ? 0.f : hv;
    }
    {
        v2h h01 = PKRTZ(huv[0], huv[1]);
        v2h h23 = PKRTZ(huv[2], huv[3]);
        v4h hw = { h01[0], h01[1], h23[0], h23[1] };
        *(v4h*)&h_lds[0][n16 * LDSS + c16] = hw;
    }

    // uniform (SGPR) stream bases + constant per-lane 32-bit byte offsets
    const int RZB = B_DIM * 256 * 2;   // bytes per t-row of gRZ
    const int NB  = B_DIM * 128 * 2;   // bytes per t-row of gN
    const int rzo = ((B0 + n16) * 256 + w * 32 + quad * 8) * 2;
    const int no_ = ((B0 + n16) * 128 + c16) * 2;
    const char* gRZc = (const char*)gRZ;
    const char* gNc  = (const char*)gN;

    // 4-deep rotating prefetch buffers, preloaded with rows 0..3
    v8h s8a = *(const v8h*)(gRZc + 0 * (size_t)RZB + rzo);
    v8h s8b = *(const v8h*)(gRZc + 1 * (size_t)RZB + rzo);
    v8h s8c = *(const v8h*)(gRZc + 2 * (size_t)RZB + rzo);
    v8h s8d = *(const v8h*)(gRZc + 3 * (size_t)RZB + rzo);
    v4h s4a = *(const v4h*)(gNc + 0 * (size_t)NB + no_);
    v4h s4b = *(const v4h*)(gNc + 1 * (size_t)NB + no_);
    v4h s4c = *(const v4h*)(gNc + 2 * (size_t)NB + no_);
    v4h s4d = *(const v4h*)(gNc + 3 * (size_t)NB + no_);

    const char* rzb = gRZc + (size_t)4 * RZB;   // prefetch base (row t+4)
    const char* nb  = gNc  + (size_t)4 * NB;
    int dpo = 16 + n16;                         // d_lds offset for done[t+1]
    bool dprev = false;                         // done[t] (h_lds[0] pre-masked)
    __syncthreads();   // h_lds[0] visible

    auto STEP = [&](int t, v8h& s8, v4h& s4,
                    const _Float16* __restrict__ hin, _Float16* __restrict__ hout)
        __attribute__((always_inline)) -> void {
        const unsigned char dnx = d_lds[dpo];

        v8h bh[4];
#pragma unroll
        for (int kt = 0; kt < 4; ++kt)
            bh[kt] = *(const v8h*)&hin[n16 * LDSS + kt * 32 + quad * 8];

        // --- inline q[t-1] on waves 0,1 (bh IS unmasked ys[t-1]) ---
        if (w < 2) {
            v4f qa = {0.f,0.f,0.f,0.f};
#pragma unroll
            for (int kt = 0; kt < 4; ++kt)
                qa = __builtin_amdgcn_mfma_f32_16x16x32_f16(fo[kt], bh[kt], qa, 0, 0, 0);
            if (t > 0) {
                float* qp = qout + ((size_t)(t - 1) * B_DIM + B0 + n16) * A_DIM;
                const int cbase = w * 16 + quad * 4;
#pragma unroll
                for (int r = 0; r < 4; ++r)
                    if (cbase + r < A_DIM) qp[cbase + r] = qa[r] + bq[r];
            }
        }

        // --- gate 0 (r) MFMA chain ---
        v4f ga0 = {0.f,0.f,0.f,0.f};
#pragma unroll
        for (int kt = 0; kt < 4; ++kt)
            ga0 = __builtin_amdgcn_mfma_f32_16x16x32_f16(fh[0][kt], bh[kt], ga0, 0, 0, 0);
        // --- gate 1 (z) MFMA chain ---
        v4f ga1 = {0.f,0.f,0.f,0.f};
#pragma unroll
        for (int kt = 0; kt < 4; ++kt)
            ga1 = __builtin_amdgcn_mfma_f32_16x16x32_f16(fh[1][kt], bh[kt], ga1, 0, 0, 0);

        // gate-mask for done rows (replaces carry masking in h_lds):
        // lane's 4 outputs all belong to batch n16 -> per-lane cndmask.
        if (dprev) { ga0 = (v4f){0.f,0.f,0.f,0.f}; ga1 = (v4f){0.f,0.f,0.f,0.f}; }

        // r-gate trans NOW: depends only on ga0; overlaps ga2 matrix-pipe time
        v2f arl = (v2f){ (float)s8[0], (float)s8[1] } + (v2f){ ga0[0], ga0[1] };
        v2f arh = (v2f){ (float)s8[2], (float)s8[3] } + (v2f){ ga0[2], ga0[3] };
        v2f rgl = { RCPF(EXP2F(arl[0]) + 1.f), RCPF(EXP2F(arl[1]) + 1.f) };
        v2f rgh = { RCPF(EXP2F(arh[0]) + 1.f), RCPF(EXP2F(arh[1]) + 1.f) };

        // --- gate 2 (n) MFMA chain, bhn in C-init ---
        v4f ga2 = bhn_c;
#pragma unroll
        for (int kt = 0; kt < 4; ++kt)
            ga2 = __builtin_amdgcn_mfma_f32_16x16x32_f16(fh[2][kt], bh[kt], ga2, 0, 0, 0);
        if (dprev) ga2 = bhn_c;

        // z-gate trans: depends only on ga1; overlaps ga2's tail
        v2f azl = (v2f){ (float)s8[4], (float)s8[5] } + (v2f){ ga1[0], ga1[1] };
        v2f azh = (v2f){ (float)s8[6], (float)s8[7] } + (v2f){ ga1[2], ga1[3] };
        v2f ezl = { EXP2F(azl[0]), EXP2F(azl[1]) };
        v2f ezh = { EXP2F(azh[0]), EXP2F(azh[1]) };

        // n-gate + fused rational: h = [ez*(en-1) + hu*(en+1)] / [(en+1)*(1+ez)]
        v2f snl = rgl * (v2f){ ga2[0], ga2[1] } + (v2f){ (float)s4[0], (float)s4[1] };
        v2f snh = rgh * (v2f){ ga2[2], ga2[3] } + (v2f){ (float)s4[2], (float)s4[3] };
        v2f enl = { EXP2F(snl[0]), EXP2F(snl[1]) };
        v2f enh = { EXP2F(snh[0]), EXP2F(snh[1]) };
        v2f enpl = enl + 1.f, enph = enh + 1.f;
        v2f enml = enl - 1.f, enmh = enh - 1.f;
        v2f hul = { huv[0], huv[1] }, huh = { huv[2], huv[3] };
        v2f numl = hul * enpl + enml * ezl;
        v2f numh = huh * enph + enmh * ezh;
        v2f denl = enpl * (ezl + 1.f);
        v2f denh = enph * (ezh + 1.f);
        v2f hnl = numl * (v2f){ RCPF(denl[0]), RCPF(denl[1]) };
        v2f hnh = numh * (v2f){ RCPF(denh[0]), RCPF(denh[1]) };

        // h_lds gets the UNMASKED ys[t]; register carry gets done[t+1] mask
        v2h y01 = PKRTZ(hnl[0], hnl[1]);
        v2h y23 = PKRTZ(hnh[0], hnh[1]);
        v4h yv = { y01[0], y01[1], y23[0], y23[1] };
        *(v4h*)&hout[n16 * LDSS + c16] = yv;
        const bool dn = dnx != 0;
#pragma unroll
        for (int r = 0; r < 4; ++r) huv[r] = dn ? 0.f : (r < 2 ? hnl[r] : hnh[r - 2]);
        dprev = dn;

        // reload THIS buffer with row t+4 (consumed 4 steps later)
        s8 = *(const v8h*)(rzb + rzo);
        s4 = *(const v4h*)(nb + no_);

        if (t < 507) { rzb += RZB; nb += NB; }
        dpo += 16;
        BAR();
    };

    for (int t = 0; t < T_DIM; t += 4) {
        STEP(t,     s8a, s4a, h_lds[0], h_lds[1]);
        STEP(t + 1, s8b, s4b, h_lds[1], h_lds[0]);
        STEP(t + 2, s8c, s4c, h_lds[0], h_lds[1]);
        STEP(t + 3, s8d, s4d, h_lds[1], h_lds[0]);
    }

    // epilogue: q[511] from h_lds[0] (written by STEP(511); BAR() done)
    if (w < 2) {
        v8h bh[4];
#pragma unroll
        for (int kt = 0; kt < 4; ++kt)
            bh[kt] = *(const v8h*)&h_lds[0][n16 * LDSS + kt * 32 + quad * 8];
        v4f qa = {0.f,0.f,0.f,0.f};
#pragma unroll
        for (int kt = 0; kt < 4; ++kt)
            qa = __builtin_amdgcn_mfma_f32_16x16x32_f16(fo[kt], bh[kt], qa, 0, 0, 0);
        float* qp = qout + ((size_t)(T_DIM - 1) * B_DIM + B0 + n16) * A_DIM;
        const int cbase = w * 16 + quad * 4;
#pragma unroll
        for (int r = 0; r < 4; ++r)
            if (cbase + r < A_DIM) qp[cbase + r] = qa[r] + bq[r];
    }

    // h_final (hu after t=511 is unmasked: d_lds row 512 zeroed)
#pragma unroll
    for (int r = 0; r < 4; ++r)
        out[(size_t)(B0 + n16) * H_DIM + c16 + r] = huv[r];
}

extern "C" void kernel_launch(void* const* d_in, const int* in_sizes, int n_in,
                              void* d_out, int out_size, void* d_ws, size_t ws_size,
                              hipStream_t stream) {
    const float* hidden = (const float*)d_in[0];
    const float* obs    = (const float*)d_in[1];
    const unsigned char* dones = (const unsigned char*)d_in[2];
    const float* W_emb  = (const float*)d_in[3];
    const float* b_emb  = (const float*)d_in[4];
    const float* Wi     = (const float*)d_in[5];
    const float* bi     = (const float*)d_in[6];
    const float* Wh     = (const float*)d_in[7];
    const float* bhn    = (const float*)d_in[8];
    const float* W_out  = (const float*)d_in[9];
    const float* b_out  = (const float*)d_in[10];
    float* out = (float*)d_out;

    _Float16* gRZ = (_Float16*)d_ws;                              // [T*B][256] f16 = 128 MiB
    _Float16* gN  = gRZ + (size_t)T_DIM * B_DIM * 256;            // [T*B][128] f16 =  64 MiB

    hipLaunchKernelGGL(k1_embed_gi, dim3(256), dim3(512), 0, stream,
                       obs, W_emb, b_emb, Wi, bi, gRZ, gN);
    hipLaunchKernelGGL(k2_recurrence, dim3(32), dim3(512), 0, stream,
                       hidden, dones, gRZ, gN, Wh, bhn, W_out, b_out, out);
}